// Round 3
// baseline (670.796 us; speedup 1.0000x reference)
//
#include <hip/hip_runtime.h>
#include <hip/hip_bf16.h>

#define B_SZ 4
#define T_SZ 2048
#define S_SZ 2048
#define D_SZ 1024
#define R_SZ 128
#define SCALE_F 0.08838834764831845f  // 1/sqrt(128)

typedef __attribute__((ext_vector_type(8))) short short8;     // 8 x bf16 (raw bits)
typedef __attribute__((ext_vector_type(4))) float f32x4;
typedef __attribute__((ext_vector_type(4))) float float4v;
typedef __attribute__((ext_vector_type(4))) unsigned short u16x4;

// fp32 -> bf16 round-to-nearest-even, raw bits
__device__ __forceinline__ unsigned short f2bf(float f) {
  unsigned int u = __float_as_uint(f);
  unsigned int r = (u + 0x7FFFu + ((u >> 16) & 1u)) >> 16;
  return (unsigned short)r;
}

__global__ __launch_bounds__(256) void cvt_f32_bf16(const float* __restrict__ in,
                                                    unsigned short* __restrict__ out,
                                                    int n4) {
  int i = blockIdx.x * blockDim.x + threadIdx.x;
  int stride = gridDim.x * blockDim.x;
  for (; i < n4; i += stride) {
    float4v v = reinterpret_cast<const float4v*>(in)[i];
    u16x4 o;
    o.x = f2bf(v.x); o.y = f2bf(v.y); o.z = f2bf(v.z); o.w = f2bf(v.w);
    reinterpret_cast<u16x4*>(out)[i] = o;
  }
}

// C[M,N] = A[M,K] * B[N,K]^T   (NT form; A,B bf16 row-major with strides lda/ldb)
// block = 256 threads = 4 waves (2x2), block tile 64x64, wave tile 32x32,
// fragments: mfma_f32_16x16x32_bf16, direct global loads (16B per lane).
template <int OUT_BF16>
__global__ __launch_bounds__(256) void gemm_nt(
    const unsigned short* __restrict__ A,
    const unsigned short* __restrict__ B,
    void* __restrict__ Cv,
    int M, int N, int K, int lda, int ldb, int ldc,
    long long sA, long long sB, long long sC) {
  A += (long long)blockIdx.z * sA;
  B += (long long)blockIdx.z * sB;

  const int lane = threadIdx.x & 63;
  const int wid  = threadIdx.x >> 6;
  const int wr = wid >> 1, wc = wid & 1;
  const int m0 = blockIdx.y * 64 + wr * 32;
  const int n0 = blockIdx.x * 64 + wc * 32;

  const int fr = lane & 15;         // row (A) / col (B) within 16
  const int ko = (lane >> 4) * 8;   // k offset within 32

  f32x4 acc[2][2] = {};

  const unsigned short* Ab = A + (long long)(m0 + fr) * lda + ko;
  const unsigned short* Bb = B + (long long)(n0 + fr) * ldb + ko;

  for (int kk = 0; kk < K; kk += 32) {
    short8 a0 = *reinterpret_cast<const short8*>(Ab + kk);
    short8 a1 = *reinterpret_cast<const short8*>(Ab + (long long)16 * lda + kk);
    short8 b0 = *reinterpret_cast<const short8*>(Bb + kk);
    short8 b1 = *reinterpret_cast<const short8*>(Bb + (long long)16 * ldb + kk);
    acc[0][0] = __builtin_amdgcn_mfma_f32_16x16x32_bf16(a0, b0, acc[0][0], 0, 0, 0);
    acc[0][1] = __builtin_amdgcn_mfma_f32_16x16x32_bf16(a0, b1, acc[0][1], 0, 0, 0);
    acc[1][0] = __builtin_amdgcn_mfma_f32_16x16x32_bf16(a1, b0, acc[1][0], 0, 0, 0);
    acc[1][1] = __builtin_amdgcn_mfma_f32_16x16x32_bf16(a1, b1, acc[1][1], 0, 0, 0);
  }

  const int cr = (lane >> 4) * 4;   // C row base within 16
  const int cc = lane & 15;         // C col within 16
#pragma unroll
  for (int mi = 0; mi < 2; mi++)
#pragma unroll
    for (int ni = 0; ni < 2; ni++)
#pragma unroll
      for (int r = 0; r < 4; r++) {
        long long row = m0 + mi * 16 + cr + r;
        long long col = n0 + ni * 16 + cc;
        float val = acc[mi][ni][r];
        if (OUT_BF16) {
          unsigned short* C = (unsigned short*)Cv + blockIdx.z * sC;
          C[row * ldc + col] = f2bf(val);
        } else {
          float* C = (float*)Cv + blockIdx.z * sC;
          C[row * ldc + col] = val;
        }
      }
}

// Row softmax over S=2048 fp32 scores; writes bf16 probs IN-PLACE at the row
// start (bf16 row stride = 2*S elements as seen by the PV GEMM).
__global__ __launch_bounds__(256) void softmax_rows(float* __restrict__ scores) {
  long long row = blockIdx.x;
  float* srow = scores + row * (long long)S_SZ;
  unsigned short* prow = (unsigned short*)srow;
  const int t = threadIdx.x;
  const int wid = t >> 6, lane = t & 63;

  float v[8];
#pragma unroll
  for (int j = 0; j < 8; j++) v[j] = srow[j * 256 + t] * SCALE_F;

  float m = v[0];
#pragma unroll
  for (int j = 1; j < 8; j++) m = fmaxf(m, v[j]);
#pragma unroll
  for (int off = 32; off; off >>= 1) m = fmaxf(m, __shfl_xor(m, off));

  __shared__ float redm[4];
  __shared__ float reds[4];
  if (lane == 0) redm[wid] = m;
  __syncthreads();  // also guarantees all loads of srow are complete
  m = fmaxf(fmaxf(redm[0], redm[1]), fmaxf(redm[2], redm[3]));

  float s = 0.f;
#pragma unroll
  for (int j = 0; j < 8; j++) {
    v[j] = __expf(v[j] - m);
    s += v[j];
  }
#pragma unroll
  for (int off = 32; off; off >>= 1) s += __shfl_xor(s, off);
  if (lane == 0) reds[wid] = s;
  __syncthreads();
  s = reds[0] + reds[1] + reds[2] + reds[3];
  float inv = 1.0f / s;

#pragma unroll
  for (int j = 0; j < 8; j++) prow[j * 256 + t] = f2bf(v[j] * inv);
}

extern "C" void kernel_launch(void* const* d_in, const int* in_sizes, int n_in,
                              void* d_out, int out_size, void* d_ws, size_t ws_size,
                              hipStream_t stream) {
  const float* tgt = (const float*)d_in[0];
  const float* mem = (const float*)d_in[1];
  const float* Wq  = (const float*)d_in[2];
  const float* Wk  = (const float*)d_in[3];
  const float* Wv  = (const float*)d_in[4];
  const float* Wo  = (const float*)d_in[5];
  float* out = (float*)d_out;

  // ---- workspace layout (all 256B-aligned sizes) ----
  char* p = (char*)d_ws;
  unsigned short* tgt_b = (unsigned short*)p; p += (size_t)B_SZ * T_SZ * D_SZ * 2;  // later reused as attn_out
  unsigned short* mem_b = (unsigned short*)p; p += (size_t)B_SZ * S_SZ * D_SZ * 2;
  unsigned short* wq_b  = (unsigned short*)p; p += (size_t)R_SZ * D_SZ * 2;
  unsigned short* wk_b  = (unsigned short*)p; p += (size_t)R_SZ * D_SZ * 2;
  unsigned short* wv_b  = (unsigned short*)p; p += (size_t)D_SZ * D_SZ * 2;
  unsigned short* wo_b  = (unsigned short*)p; p += (size_t)D_SZ * D_SZ * 2;
  unsigned short* q_b   = (unsigned short*)p; p += (size_t)B_SZ * T_SZ * R_SZ * 2;
  unsigned short* k_b   = (unsigned short*)p; p += (size_t)B_SZ * S_SZ * R_SZ * 2;
  unsigned short* vT_b  = (unsigned short*)p; p += (size_t)B_SZ * D_SZ * S_SZ * 2;
  float* scores = (float*)p;                  p += (size_t)B_SZ * T_SZ * S_SZ * 4;

  // ---- fp32 -> bf16 conversions ----
  auto cvt = [&](const float* src, unsigned short* dst, long long n) {
    int n4 = (int)(n / 4);
    int grid = (n4 + 255) / 256;
    if (grid > 2048) grid = 2048;
    cvt_f32_bf16<<<dim3(grid), dim3(256), 0, stream>>>(src, dst, n4);
  };
  cvt(tgt, tgt_b, (long long)B_SZ * T_SZ * D_SZ);
  cvt(mem, mem_b, (long long)B_SZ * S_SZ * D_SZ);
  cvt(Wq, wq_b, (long long)R_SZ * D_SZ);
  cvt(Wk, wk_b, (long long)R_SZ * D_SZ);
  cvt(Wv, wv_b, (long long)D_SZ * D_SZ);
  cvt(Wo, wo_b, (long long)D_SZ * D_SZ);

  dim3 blk(256);

  // q = tgt @ Wq^T : [B,T,R]
  gemm_nt<1><<<dim3(R_SZ / 64, T_SZ / 64, B_SZ), blk, 0, stream>>>(
      tgt_b, wq_b, q_b, T_SZ, R_SZ, D_SZ, D_SZ, D_SZ, R_SZ,
      (long long)T_SZ * D_SZ, 0LL, (long long)T_SZ * R_SZ);

  // k = mem @ Wk^T : [B,S,R]
  gemm_nt<1><<<dim3(R_SZ / 64, S_SZ / 64, B_SZ), blk, 0, stream>>>(
      mem_b, wk_b, k_b, S_SZ, R_SZ, D_SZ, D_SZ, D_SZ, R_SZ,
      (long long)S_SZ * D_SZ, 0LL, (long long)S_SZ * R_SZ);

  // vT = Wv @ mem^T : [B,D,S]   (so PV is NT form too)
  gemm_nt<1><<<dim3(S_SZ / 64, D_SZ / 64, B_SZ), blk, 0, stream>>>(
      wv_b, mem_b, vT_b, D_SZ, S_SZ, D_SZ, D_SZ, D_SZ, S_SZ,
      0LL, (long long)S_SZ * D_SZ, (long long)D_SZ * S_SZ);

  // scores = q @ k^T : [B,T,S] fp32 (scale applied in softmax)
  gemm_nt<0><<<dim3(S_SZ / 64, T_SZ / 64, B_SZ), blk, 0, stream>>>(
      q_b, k_b, scores, T_SZ, S_SZ, R_SZ, R_SZ, R_SZ, S_SZ,
      (long long)T_SZ * R_SZ, (long long)S_SZ * R_SZ, (long long)T_SZ * S_SZ);

  // softmax rows, bf16 probs in-place (row stride 2*S bf16 elements)
  softmax_rows<<<dim3(B_SZ * T_SZ), blk, 0, stream>>>(scores);

  // attn_out = probs @ vT^T : [B,T,D]  (reuse tgt_b buffer)
  gemm_nt<1><<<dim3(D_SZ / 64, T_SZ / 64, B_SZ), blk, 0, stream>>>(
      (const unsigned short*)scores, vT_b, tgt_b, T_SZ, D_SZ, S_SZ,
      2 * S_SZ, S_SZ, D_SZ,
      2LL * T_SZ * S_SZ, (long long)D_SZ * S_SZ, (long long)T_SZ * D_SZ);

  // out = attn_out @ Wo^T : [B,T,D] fp32 -> d_out
  gemm_nt<0><<<dim3(D_SZ / 64, T_SZ / 64, B_SZ), blk, 0, stream>>>(
      tgt_b, wo_b, out, T_SZ, D_SZ, D_SZ, D_SZ, D_SZ, D_SZ,
      (long long)T_SZ * D_SZ, 0LL, (long long)T_SZ * D_SZ);
}

// Round 6
// 336.934 us; speedup vs baseline: 1.9909x; 1.9909x over previous
//
#include <hip/hip_runtime.h>
#include <hip/hip_bf16.h>

#define B_SZ 4
#define T_SZ 2048
#define S_SZ 2048
#define D_SZ 1024
#define R_SZ 128
#define SCALE_F 0.08838834764831845f  // 1/sqrt(128)

typedef __attribute__((ext_vector_type(8))) short short8;     // 8 x bf16 (raw bits)
typedef __attribute__((ext_vector_type(4))) float f32x4;
typedef __attribute__((ext_vector_type(4))) float float4v;
typedef __attribute__((ext_vector_type(4))) unsigned short u16x4;

// fp32 -> bf16 round-to-nearest-even, raw bits
__device__ __forceinline__ unsigned short f2bf(float f) {
  unsigned int u = __float_as_uint(f);
  unsigned int r = (u + 0x7FFFu + ((u >> 16) & 1u)) >> 16;
  return (unsigned short)r;
}

// async global->LDS, 16B per lane. LDS dest is wave-uniform base + lane*16.
__device__ __forceinline__ void gload_lds16(const unsigned short* g, unsigned short* l) {
  __builtin_amdgcn_global_load_lds(
      (const __attribute__((address_space(1))) unsigned int*)g,
      (__attribute__((address_space(3))) unsigned int*)l, 16, 0, 0);
}

__global__ __launch_bounds__(256) void cvt_f32_bf16(const float* __restrict__ in,
                                                    unsigned short* __restrict__ out,
                                                    int n4) {
  int i = blockIdx.x * blockDim.x + threadIdx.x;
  int stride = gridDim.x * blockDim.x;
  for (; i < n4; i += stride) {
    float4v v = reinterpret_cast<const float4v*>(in)[i];
    u16x4 o;
    o.x = f2bf(v.x); o.y = f2bf(v.y); o.z = f2bf(v.z); o.w = f2bf(v.w);
    reinterpret_cast<u16x4*>(out)[i] = o;
  }
}

// C[M,N] = A[M,K] * B[N,K]^T  (NT form, bf16 in, fp32 acc).
// m97 structure: 128x128 block tile, BK=32, 4 waves (2x2) x 64x64 wave tile,
// 4x4 fragments of mfma_f32_16x16x32_bf16, global_load_lds width-16 staging,
// 2-barrier K-loop. M,N must be multiples of 128, K of 32.
template <int OUT_BF16>
__global__ __launch_bounds__(256) void gemm_nt128(
    const unsigned short* __restrict__ A,
    const unsigned short* __restrict__ B,
    void* __restrict__ Cv,
    int K, int lda, int ldb, int ldc,
    long long sA, long long sB, long long sC) {
  __shared__ unsigned short sAB[8192];  // A tile [128][32] @0, B tile [128][32] @4096

  const int t = threadIdx.x;
  const int lane = t & 63;
  const int wid = t >> 6;
  const int wr = wid >> 1, wc = wid & 1;
  const long long m0b = (long long)blockIdx.y * 128;
  const long long n0b = (long long)blockIdx.x * 128;

  A += (long long)blockIdx.z * sA;
  B += (long long)blockIdx.z * sB;

  // ---- staging source pointers (per-thread): row = base + t/4, col = (t&3)*8
  const unsigned short* As0 = A + (m0b + (t >> 2)) * (long long)lda + (t & 3) * 8;
  const unsigned short* As1 = As0 + 64LL * lda;
  const unsigned short* Bs0 = B + (n0b + (t >> 2)) * (long long)ldb + (t & 3) * 8;
  const unsigned short* Bs1 = Bs0 + 64LL * ldb;

  // ---- staging LDS dests (wave-uniform): chunk c covers rows c*64..c*64+63,
  // linear bytes c*4096 + wave*1024 + lane*16
  unsigned short* lA = sAB;
  unsigned short* lB = sAB + 4096;
  unsigned short* lA0 = lA + wid * 512;
  unsigned short* lA1 = lA0 + 2048;
  unsigned short* lB0 = lB + wid * 512;
  unsigned short* lB1 = lB0 + 2048;

  // ---- fragment read bases: row stride 32 elements (64B)
  const int fr = lane & 15;
  const int ko = (lane >> 4) * 8;  // k element offset within 32
  const unsigned short* aF = lA + (wr * 64 + fr) * 32 + ko;
  const unsigned short* bF = lB + (wc * 64 + fr) * 32 + ko;

  f32x4 acc[4][4] = {};

  for (int k0 = 0; k0 < K; k0 += 32) {
    gload_lds16(As0 + k0, lA0);
    gload_lds16(As1 + k0, lA1);
    gload_lds16(Bs0 + k0, lB0);
    gload_lds16(Bs1 + k0, lB1);
    __syncthreads();  // drains vmcnt -> tiles resident

    short8 a[4], b[4];
#pragma unroll
    for (int i = 0; i < 4; i++) {
      a[i] = *reinterpret_cast<const short8*>(aF + i * 512);  // +16 rows
      b[i] = *reinterpret_cast<const short8*>(bF + i * 512);
    }
#pragma unroll
    for (int mi = 0; mi < 4; mi++)
#pragma unroll
      for (int ni = 0; ni < 4; ni++)
        acc[mi][ni] =
            __builtin_amdgcn_mfma_f32_16x16x32_bf16(a[mi], b[ni], acc[mi][ni], 0, 0, 0);
    __syncthreads();  // LDS reads done before next-iter staging overwrites
  }

  // ---- epilogue: C/D mapping col=lane&15, row=(lane>>4)*4+r (verified)
  const int cr = (lane >> 4) * 4;
  const int cc = lane & 15;
#pragma unroll
  for (int mi = 0; mi < 4; mi++)
#pragma unroll
    for (int ni = 0; ni < 4; ni++)
#pragma unroll
      for (int r = 0; r < 4; r++) {
        long long row = m0b + wr * 64 + mi * 16 + cr + r;
        long long col = n0b + wc * 64 + ni * 16 + cc;
        float val = acc[mi][ni][r];
        if (OUT_BF16) {
          unsigned short* C = (unsigned short*)Cv + blockIdx.z * sC;
          C[row * ldc + col] = f2bf(val);
        } else {
          float* C = (float*)Cv + blockIdx.z * sC;
          C[row * ldc + col] = val;
        }
      }
}

// Row softmax over S=2048 fp32 scores; writes bf16 probs IN-PLACE at the row
// start (bf16 row stride = 2*S elements as seen by the PV GEMM).
// Vectorized: float4 loads, ushort4 stores.
__global__ __launch_bounds__(256) void softmax_rows(float* __restrict__ scores) {
  long long row = blockIdx.x;
  float* srow = scores + row * (long long)S_SZ;
  const int t = threadIdx.x;
  const int wid = t >> 6, lane = t & 63;

  float4v va = reinterpret_cast<const float4v*>(srow)[t];
  float4v vb = reinterpret_cast<const float4v*>(srow)[t + 256];
  float v[8] = {va.x * SCALE_F, va.y * SCALE_F, va.z * SCALE_F, va.w * SCALE_F,
                vb.x * SCALE_F, vb.y * SCALE_F, vb.z * SCALE_F, vb.w * SCALE_F};

  float m = v[0];
#pragma unroll
  for (int j = 1; j < 8; j++) m = fmaxf(m, v[j]);
#pragma unroll
  for (int off = 32; off; off >>= 1) m = fmaxf(m, __shfl_xor(m, off));

  __shared__ float redm[4];
  __shared__ float reds[4];
  if (lane == 0) redm[wid] = m;
  __syncthreads();  // also guarantees all loads of srow completed before stores
  m = fmaxf(fmaxf(redm[0], redm[1]), fmaxf(redm[2], redm[3]));

  float s = 0.f;
#pragma unroll
  for (int j = 0; j < 8; j++) {
    v[j] = __expf(v[j] - m);
    s += v[j];
  }
#pragma unroll
  for (int off = 32; off; off >>= 1) s += __shfl_xor(s, off);
  if (lane == 0) reds[wid] = s;
  __syncthreads();
  s = reds[0] + reds[1] + reds[2] + reds[3];
  float inv = 1.0f / s;

  u16x4 oa, ob;
  oa.x = f2bf(v[0] * inv); oa.y = f2bf(v[1] * inv);
  oa.z = f2bf(v[2] * inv); oa.w = f2bf(v[3] * inv);
  ob.x = f2bf(v[4] * inv); ob.y = f2bf(v[5] * inv);
  ob.z = f2bf(v[6] * inv); ob.w = f2bf(v[7] * inv);
  u16x4* prow4 = reinterpret_cast<u16x4*>(srow);
  prow4[t] = oa;
  prow4[t + 256] = ob;
}

extern "C" void kernel_launch(void* const* d_in, const int* in_sizes, int n_in,
                              void* d_out, int out_size, void* d_ws, size_t ws_size,
                              hipStream_t stream) {
  const float* tgt = (const float*)d_in[0];
  const float* mem = (const float*)d_in[1];
  const float* Wq  = (const float*)d_in[2];
  const float* Wk  = (const float*)d_in[3];
  const float* Wv  = (const float*)d_in[4];
  const float* Wo  = (const float*)d_in[5];
  float* out = (float*)d_out;

  // ---- workspace layout ----
  char* p = (char*)d_ws;
  unsigned short* tgt_b = (unsigned short*)p; p += (size_t)B_SZ * T_SZ * D_SZ * 2;  // reused as attn_out
  unsigned short* mem_b = (unsigned short*)p; p += (size_t)B_SZ * S_SZ * D_SZ * 2;
  unsigned short* wq_b  = (unsigned short*)p; p += (size_t)R_SZ * D_SZ * 2;
  unsigned short* wk_b  = (unsigned short*)p; p += (size_t)R_SZ * D_SZ * 2;
  unsigned short* wv_b  = (unsigned short*)p; p += (size_t)D_SZ * D_SZ * 2;
  unsigned short* wo_b  = (unsigned short*)p; p += (size_t)D_SZ * D_SZ * 2;
  unsigned short* q_b   = (unsigned short*)p; p += (size_t)B_SZ * T_SZ * R_SZ * 2;
  unsigned short* k_b   = (unsigned short*)p; p += (size_t)B_SZ * S_SZ * R_SZ * 2;
  unsigned short* vT_b  = (unsigned short*)p; p += (size_t)B_SZ * D_SZ * S_SZ * 2;
  float* scores = (float*)p;                  p += (size_t)B_SZ * T_SZ * S_SZ * 4;

  // ---- fp32 -> bf16 conversions ----
  auto cvt = [&](const float* src, unsigned short* dst, long long n) {
    int n4 = (int)(n / 4);
    int grid = (n4 + 255) / 256;
    if (grid > 2048) grid = 2048;
    cvt_f32_bf16<<<dim3(grid), dim3(256), 0, stream>>>(src, dst, n4);
  };
  cvt(tgt, tgt_b, (long long)B_SZ * T_SZ * D_SZ);
  cvt(mem, mem_b, (long long)B_SZ * S_SZ * D_SZ);
  cvt(Wq, wq_b, (long long)R_SZ * D_SZ);
  cvt(Wk, wk_b, (long long)R_SZ * D_SZ);
  cvt(Wv, wv_b, (long long)D_SZ * D_SZ);
  cvt(Wo, wo_b, (long long)D_SZ * D_SZ);

  dim3 blk(256);

  // q = tgt @ Wq^T : [B,T,R]
  gemm_nt128<1><<<dim3(R_SZ / 128, T_SZ / 128, B_SZ), blk, 0, stream>>>(
      tgt_b, wq_b, q_b, D_SZ, D_SZ, D_SZ, R_SZ,
      (long long)T_SZ * D_SZ, 0LL, (long long)T_SZ * R_SZ);

  // k = mem @ Wk^T : [B,S,R]
  gemm_nt128<1><<<dim3(R_SZ / 128, S_SZ / 128, B_SZ), blk, 0, stream>>>(
      mem_b, wk_b, k_b, D_SZ, D_SZ, D_SZ, R_SZ,
      (long long)S_SZ * D_SZ, 0LL, (long long)S_SZ * R_SZ);

  // vT = Wv @ mem^T : [B,D,S]   (so PV is NT form too)
  gemm_nt128<1><<<dim3(S_SZ / 128, D_SZ / 128, B_SZ), blk, 0, stream>>>(
      wv_b, mem_b, vT_b, D_SZ, D_SZ, D_SZ, S_SZ,
      0LL, (long long)S_SZ * D_SZ, (long long)D_SZ * S_SZ);

  // scores = q @ k^T : [B,T,S] fp32 (scale applied in softmax)
  gemm_nt128<0><<<dim3(S_SZ / 128, T_SZ / 128, B_SZ), blk, 0, stream>>>(
      q_b, k_b, scores, R_SZ, R_SZ, R_SZ, S_SZ,
      (long long)T_SZ * R_SZ, (long long)S_SZ * R_SZ, (long long)T_SZ * S_SZ);

  // softmax rows, bf16 probs in-place (row stride 2*S bf16 elements)
  softmax_rows<<<dim3(B_SZ * T_SZ), blk, 0, stream>>>(scores);

  // attn_out = probs @ vT^T : [B,T,D]  (reuse tgt_b buffer)
  gemm_nt128<1><<<dim3(D_SZ / 128, T_SZ / 128, B_SZ), blk, 0, stream>>>(
      (const unsigned short*)scores, vT_b, tgt_b, S_SZ, 2 * S_SZ, S_SZ, D_SZ,
      2LL * T_SZ * S_SZ, (long long)D_SZ * S_SZ, (long long)T_SZ * D_SZ);

  // out = attn_out @ Wo^T : [B,T,D] fp32 -> d_out
  gemm_nt128<0><<<dim3(D_SZ / 128, T_SZ / 128, B_SZ), blk, 0, stream>>>(
      tgt_b, wo_b, out, D_SZ, D_SZ, D_SZ, D_SZ,
      (long long)T_SZ * D_SZ, 0LL, (long long)T_SZ * D_SZ);
}

// Round 7
// 286.062 us; speedup vs baseline: 2.3449x; 1.1778x over previous
//
#include <hip/hip_runtime.h>
#include <hip/hip_bf16.h>

#define B_SZ 4
#define T_SZ 2048
#define S_SZ 2048
#define D_SZ 1024
#define R_SZ 128
#define SCALE_F 0.08838834764831845f  // 1/sqrt(128)

typedef __attribute__((ext_vector_type(8))) short short8;     // 8 x bf16 (raw bits)
typedef __attribute__((ext_vector_type(4))) float f32x4;
typedef __attribute__((ext_vector_type(4))) float float4v;
typedef __attribute__((ext_vector_type(4))) unsigned short u16x4;

// fp32 -> bf16 round-to-nearest-even, raw bits
__device__ __forceinline__ unsigned short f2bf(float f) {
  unsigned int u = __float_as_uint(f);
  unsigned int r = (u + 0x7FFFu + ((u >> 16) & 1u)) >> 16;
  return (unsigned short)r;
}

// async global->LDS, 16B per lane. LDS dest is wave-uniform base + lane*16.
__device__ __forceinline__ void gload_lds16(const unsigned short* g, unsigned short* l) {
  __builtin_amdgcn_global_load_lds(
      (const __attribute__((address_space(1))) unsigned int*)g,
      (__attribute__((address_space(3))) unsigned int*)l, 16, 0, 0);
}

__global__ __launch_bounds__(256) void cvt_f32_bf16(const float* __restrict__ in,
                                                    unsigned short* __restrict__ out,
                                                    int n4) {
  int i = blockIdx.x * blockDim.x + threadIdx.x;
  int stride = gridDim.x * blockDim.x;
  for (; i < n4; i += stride) {
    float4v v = reinterpret_cast<const float4v*>(in)[i];
    u16x4 o;
    o.x = f2bf(v.x); o.y = f2bf(v.y); o.z = f2bf(v.z); o.w = f2bf(v.w);
    reinterpret_cast<u16x4*>(out)[i] = o;
  }
}

// C[M,N] = A[M,K] * B[N,K]^T  (NT form, bf16 in, fp32 acc).
// 128x128 block tile, BK=32, 4 waves (2x2) x 64x64 wave tile, 4x4 fragments of
// mfma_f32_16x16x32_bf16, global_load_lds width-16 staging.
// 2-phase double-buffered K-loop (T3-minimum): stage(t+1) issued BEFORE
// compute(t), ONE __syncthreads per K-step (vmcnt drain overlapped by MFMAs).
// B batch offset = (z >> bzs) * sB  (bzs=2 lets one launch do q&k with
// adjacent tgt/mem inputs and adjacent Wq/Wk weights).
// M,N multiples of 128; K multiple of 64.
template <int OUT_BF16>
__global__ __launch_bounds__(256) void gemm_nt128(
    const unsigned short* __restrict__ A,
    const unsigned short* __restrict__ B,
    void* __restrict__ Cv,
    int K, int lda, int ldb, int ldc, int bzs,
    long long sA, long long sB, long long sC) {
  __shared__ unsigned short sAB[2][8192];  // per buf: A tile [128][32] @0, B tile @4096

  const int t = threadIdx.x;
  const int lane = t & 63;
  const int wid = t >> 6;
  const int wr = wid >> 1, wc = wid & 1;
  const long long m0b = (long long)blockIdx.y * 128;
  const long long n0b = (long long)blockIdx.x * 128;

  A += (long long)blockIdx.z * sA;
  B += (long long)(blockIdx.z >> bzs) * sB;

  // staging source pointers (per-thread): row = base + t/4, col = (t&3)*8
  const unsigned short* As0 = A + (m0b + (t >> 2)) * (long long)lda + (t & 3) * 8;
  const unsigned short* As1 = As0 + 64LL * lda;
  const unsigned short* Bs0 = B + (n0b + (t >> 2)) * (long long)ldb + (t & 3) * 8;
  const unsigned short* Bs1 = Bs0 + 64LL * ldb;

  const int fr = lane & 15;
  const int ko = (lane >> 4) * 8;  // k element offset within 32

  f32x4 acc[4][4] = {};

  // LDS dests are wave-uniform (base + wid*1024B); HW adds lane*16B (rule #21:
  // linear dest; source pre-arranged so lane l covers row t>>2, col (t&3)*8).
  auto stage = [&](int k0, unsigned short* buf) {
    unsigned short* d = buf + wid * 512;
    gload_lds16(As0 + k0, d);            // A rows 0..63
    gload_lds16(As1 + k0, d + 2048);     // A rows 64..127
    gload_lds16(Bs0 + k0, d + 4096);     // B rows 0..63
    gload_lds16(Bs1 + k0, d + 6144);     // B rows 64..127
  };
  auto compute = [&](const unsigned short* buf) {
    const unsigned short* aF = buf + (wr * 64 + fr) * 32 + ko;
    const unsigned short* bF = buf + 4096 + (wc * 64 + fr) * 32 + ko;
    short8 a[4], b[4];
#pragma unroll
    for (int i = 0; i < 4; i++) {
      a[i] = *reinterpret_cast<const short8*>(aF + i * 512);  // +16 rows
      b[i] = *reinterpret_cast<const short8*>(bF + i * 512);
    }
#pragma unroll
    for (int mi = 0; mi < 4; mi++)
#pragma unroll
      for (int ni = 0; ni < 4; ni++)
        acc[mi][ni] =
            __builtin_amdgcn_mfma_f32_16x16x32_bf16(a[mi], b[ni], acc[mi][ni], 0, 0, 0);
  };

  stage(0, sAB[0]);
  __syncthreads();  // buf0 resident
  for (int k0 = 0; k0 < K; k0 += 64) {
    stage(k0 + 32, sAB[1]);            // in flight during compute (K%64==0 -> in bounds)
    compute(sAB[0]);
    __syncthreads();                   // drains vmcnt -> buf1 resident; buf0 reads done
    const int kn = (k0 + 64 < K) ? k0 + 64 : 0;  // last iter: harmless re-stage of 0
    stage(kn, sAB[0]);
    compute(sAB[1]);
    __syncthreads();
  }

  // epilogue: C/D mapping col=lane&15, row=(lane>>4)*4+r (verified)
  const int cr = (lane >> 4) * 4;
  const int cc = lane & 15;
#pragma unroll
  for (int mi = 0; mi < 4; mi++)
#pragma unroll
    for (int ni = 0; ni < 4; ni++)
#pragma unroll
      for (int r = 0; r < 4; r++) {
        long long row = m0b + wr * 64 + mi * 16 + cr + r;
        long long col = n0b + wc * 64 + ni * 16 + cc;
        float val = acc[mi][ni][r];
        if (OUT_BF16) {
          unsigned short* C = (unsigned short*)Cv + blockIdx.z * sC;
          C[row * ldc + col] = f2bf(val);
        } else {
          float* C = (float*)Cv + blockIdx.z * sC;
          C[row * ldc + col] = val;
        }
      }
}

// Row softmax over S=2048 fp32 scores; writes bf16 probs IN-PLACE at the row
// start (bf16 row stride = 2*S elements as seen by the PV GEMM).
__global__ __launch_bounds__(256) void softmax_rows(float* __restrict__ scores) {
  long long row = blockIdx.x;
  float* srow = scores + row * (long long)S_SZ;
  const int t = threadIdx.x;
  const int wid = t >> 6, lane = t & 63;

  float4v va = reinterpret_cast<const float4v*>(srow)[t];
  float4v vb = reinterpret_cast<const float4v*>(srow)[t + 256];
  float v[8] = {va.x * SCALE_F, va.y * SCALE_F, va.z * SCALE_F, va.w * SCALE_F,
                vb.x * SCALE_F, vb.y * SCALE_F, vb.z * SCALE_F, vb.w * SCALE_F};

  float m = v[0];
#pragma unroll
  for (int j = 1; j < 8; j++) m = fmaxf(m, v[j]);
#pragma unroll
  for (int off = 32; off; off >>= 1) m = fmaxf(m, __shfl_xor(m, off));

  __shared__ float redm[4];
  __shared__ float reds[4];
  if (lane == 0) redm[wid] = m;
  __syncthreads();  // also guarantees all loads of srow completed before stores
  m = fmaxf(fmaxf(redm[0], redm[1]), fmaxf(redm[2], redm[3]));

  float s = 0.f;
#pragma unroll
  for (int j = 0; j < 8; j++) {
    v[j] = __expf(v[j] - m);
    s += v[j];
  }
#pragma unroll
  for (int off = 32; off; off >>= 1) s += __shfl_xor(s, off);
  if (lane == 0) reds[wid] = s;
  __syncthreads();
  s = reds[0] + reds[1] + reds[2] + reds[3];
  float inv = 1.0f / s;

  u16x4 oa, ob;
  oa.x = f2bf(v[0] * inv); oa.y = f2bf(v[1] * inv);
  oa.z = f2bf(v[2] * inv); oa.w = f2bf(v[3] * inv);
  ob.x = f2bf(v[4] * inv); ob.y = f2bf(v[5] * inv);
  ob.z = f2bf(v[6] * inv); ob.w = f2bf(v[7] * inv);
  u16x4* prow4 = reinterpret_cast<u16x4*>(srow);
  prow4[t] = oa;
  prow4[t + 256] = ob;
}

extern "C" void kernel_launch(void* const* d_in, const int* in_sizes, int n_in,
                              void* d_out, int out_size, void* d_ws, size_t ws_size,
                              hipStream_t stream) {
  const float* tgt = (const float*)d_in[0];
  const float* mem = (const float*)d_in[1];
  const float* Wq  = (const float*)d_in[2];
  const float* Wk  = (const float*)d_in[3];
  const float* Wv  = (const float*)d_in[4];
  const float* Wo  = (const float*)d_in[5];
  float* out = (float*)d_out;

  // ---- workspace layout ----
  // NOTE: tgt_b/mem_b adjacent, wq_b/wk_b adjacent, q_b/k_b adjacent — the
  // merged q+k launch relies on this (grid.z = 8, z>=4 lands in mem/Wk/k).
  char* p = (char*)d_ws;
  unsigned short* tgt_b = (unsigned short*)p; p += (size_t)B_SZ * T_SZ * D_SZ * 2;  // reused as attn_out
  unsigned short* mem_b = (unsigned short*)p; p += (size_t)B_SZ * S_SZ * D_SZ * 2;
  unsigned short* wq_b  = (unsigned short*)p; p += (size_t)R_SZ * D_SZ * 2;
  unsigned short* wk_b  = (unsigned short*)p; p += (size_t)R_SZ * D_SZ * 2;
  unsigned short* wv_b  = (unsigned short*)p; p += (size_t)D_SZ * D_SZ * 2;
  unsigned short* wo_b  = (unsigned short*)p; p += (size_t)D_SZ * D_SZ * 2;
  unsigned short* q_b   = (unsigned short*)p; p += (size_t)B_SZ * T_SZ * R_SZ * 2;
  unsigned short* k_b   = (unsigned short*)p; p += (size_t)B_SZ * S_SZ * R_SZ * 2;
  unsigned short* vT_b  = (unsigned short*)p; p += (size_t)B_SZ * D_SZ * S_SZ * 2;
  float* scores = (float*)p;                  p += (size_t)B_SZ * T_SZ * S_SZ * 4;

  // ---- fp32 -> bf16 conversions ----
  auto cvt = [&](const float* src, unsigned short* dst, long long n) {
    int n4 = (int)(n / 4);
    int grid = (n4 + 255) / 256;
    if (grid > 2048) grid = 2048;
    cvt_f32_bf16<<<dim3(grid), dim3(256), 0, stream>>>(src, dst, n4);
  };
  cvt(tgt, tgt_b, (long long)B_SZ * T_SZ * D_SZ);
  cvt(mem, mem_b, (long long)B_SZ * S_SZ * D_SZ);
  cvt(Wq, wq_b, (long long)R_SZ * D_SZ);
  cvt(Wk, wk_b, (long long)R_SZ * D_SZ);
  cvt(Wv, wv_b, (long long)D_SZ * D_SZ);
  cvt(Wo, wo_b, (long long)D_SZ * D_SZ);

  dim3 blk(256);

  // q & k merged: z<4 -> q = tgt@Wq^T ; z>=4 -> k = mem@Wk^T  (bzs=2)
  gemm_nt128<1><<<dim3(R_SZ / 128, T_SZ / 128, 2 * B_SZ), blk, 0, stream>>>(
      tgt_b, wq_b, q_b, D_SZ, D_SZ, D_SZ, R_SZ, 2,
      (long long)T_SZ * D_SZ, (long long)R_SZ * D_SZ, (long long)T_SZ * R_SZ);

  // vT = Wv @ mem^T : [B,D,S]   (so PV is NT form too)
  gemm_nt128<1><<<dim3(S_SZ / 128, D_SZ / 128, B_SZ), blk, 0, stream>>>(
      wv_b, mem_b, vT_b, D_SZ, D_SZ, D_SZ, S_SZ, 0,
      0LL, (long long)S_SZ * D_SZ, (long long)D_SZ * S_SZ);

  // scores = q @ k^T : [B,T,S] fp32 (scale applied in softmax)
  gemm_nt128<0><<<dim3(S_SZ / 128, T_SZ / 128, B_SZ), blk, 0, stream>>>(
      q_b, k_b, scores, R_SZ, R_SZ, R_SZ, S_SZ, 0,
      (long long)T_SZ * R_SZ, (long long)S_SZ * R_SZ, (long long)T_SZ * S_SZ);

  // softmax rows, bf16 probs in-place (row stride 2*S bf16 elements)
  softmax_rows<<<dim3(B_SZ * T_SZ), blk, 0, stream>>>(scores);

  // attn_out = probs @ vT^T : [B,T,D]  (reuse tgt_b buffer)
  gemm_nt128<1><<<dim3(D_SZ / 128, T_SZ / 128, B_SZ), blk, 0, stream>>>(
      (const unsigned short*)scores, vT_b, tgt_b, S_SZ, 2 * S_SZ, S_SZ, D_SZ, 0,
      2LL * T_SZ * S_SZ, (long long)D_SZ * S_SZ, (long long)T_SZ * D_SZ);

  // out = attn_out @ Wo^T : [B,T,D] fp32 -> d_out
  gemm_nt128<0><<<dim3(D_SZ / 128, T_SZ / 128, B_SZ), blk, 0, stream>>>(
      tgt_b, wo_b, out, D_SZ, D_SZ, D_SZ, D_SZ, 0,
      (long long)T_SZ * D_SZ, 0LL, (long long)T_SZ * D_SZ);
}

// Round 8
// 274.768 us; speedup vs baseline: 2.4413x; 1.0411x over previous
//
#include <hip/hip_runtime.h>
#include <hip/hip_bf16.h>

#define B_SZ 4
#define T_SZ 2048
#define S_SZ 2048
#define D_SZ 1024
#define R_SZ 128
#define SCALE_F 0.08838834764831845f  // 1/sqrt(128)

typedef __attribute__((ext_vector_type(8))) short short8;     // 8 x bf16 (raw bits)
typedef __attribute__((ext_vector_type(4))) float f32x4;
typedef __attribute__((ext_vector_type(4))) float float4v;
typedef __attribute__((ext_vector_type(4))) unsigned short u16x4;

// fp32 -> bf16 round-to-nearest-even, raw bits
__device__ __forceinline__ unsigned short f2bf(float f) {
  unsigned int u = __float_as_uint(f);
  unsigned int r = (u + 0x7FFFu + ((u >> 16) & 1u)) >> 16;
  return (unsigned short)r;
}

// async global->LDS, 16B per lane. LDS dest is wave-uniform base + lane*16.
__device__ __forceinline__ void gload_lds16(const unsigned short* g, unsigned short* l) {
  __builtin_amdgcn_global_load_lds(
      (const __attribute__((address_space(1))) unsigned int*)g,
      (__attribute__((address_space(3))) unsigned int*)l, 16, 0, 0);
}

// paired fp32->bf16 conversion: blockIdx.z selects (a->oa) or (b->ob)
__global__ __launch_bounds__(256) void cvt_f32_bf16_x2(
    const float* __restrict__ a, const float* __restrict__ b,
    unsigned short* __restrict__ oa, unsigned short* __restrict__ ob, int n4) {
  const float* src = blockIdx.z ? b : a;
  unsigned short* dst = blockIdx.z ? ob : oa;
  int i = blockIdx.x * blockDim.x + threadIdx.x;
  int stride = gridDim.x * blockDim.x;
  for (; i < n4; i += stride) {
    float4v v = reinterpret_cast<const float4v*>(src)[i];
    u16x4 o;
    o.x = f2bf(v.x); o.y = f2bf(v.y); o.z = f2bf(v.z); o.w = f2bf(v.w);
    reinterpret_cast<u16x4*>(dst)[i] = o;
  }
}

// C[M,N] = A[M,K] * B[N,K]^T  (NT form, bf16 in, fp32 acc).
// 128x128 block tile, BK=32, 4 waves (2x2) x 64x64 wave tile, 4x4 fragments of
// mfma_f32_16x16x32_bf16, global_load_lds width-16 staging, 2-phase
// double-buffered K-loop (one __syncthreads per K-step).
// TAG: distinguishes instantiations in rocprof. SWZ (T1 XCD swizzle, assumes
// XCD = blockIdx % 8 round-robin; perf-only): 0 = plain 3D grid; else launch
// 1D grid of GX*GY*GZ (%8==0) blocks and decode chunked:
//   1 = x-slowest (colocate same-bx blocks per XCD; B-panel shared)
//   2 = y-slowest (A-panel shared), 3 = z-slowest (batch shared).
template <int OUT_BF16, int TAG, int SWZ>
__global__ __launch_bounds__(256) void gemm_nt128(
    const unsigned short* __restrict__ A,
    const unsigned short* __restrict__ B,
    void* __restrict__ Cv,
    int K, int lda, int ldb, int ldc, int bzs,
    long long sA, long long sB, long long sC,
    int GX, int GY, int GZ) {
  __shared__ unsigned short sAB[2][8192];  // per buf: A tile [128][32] @0, B tile @4096

  int bx, by, bz;
  if (SWZ == 0) {
    bx = blockIdx.x; by = blockIdx.y; bz = blockIdx.z;
  } else {
    const int cpx = (GX * GY * GZ) >> 3;
    const int lid = ((int)blockIdx.x & 7) * cpx + ((int)blockIdx.x >> 3);
    if (SWZ == 1) {
      bx = lid / (GY * GZ); int r = lid - bx * (GY * GZ); bz = r / GY; by = r - bz * GY;
    } else if (SWZ == 2) {
      by = lid / (GX * GZ); int r = lid - by * (GX * GZ); bz = r / GX; bx = r - bz * GX;
    } else {
      bz = lid / (GX * GY); int r = lid - bz * (GX * GY); by = r / GX; bx = r - by * GX;
    }
  }

  const int t = threadIdx.x;
  const int lane = t & 63;
  const int wid = t >> 6;
  const int wr = wid >> 1, wc = wid & 1;
  const long long m0b = (long long)by * 128;
  const long long n0b = (long long)bx * 128;

  A += (long long)bz * sA;
  B += (long long)(bz >> bzs) * sB;

  // staging source pointers (per-thread): row = base + t/4, col = (t&3)*8
  const unsigned short* As0 = A + (m0b + (t >> 2)) * (long long)lda + (t & 3) * 8;
  const unsigned short* As1 = As0 + 64LL * lda;
  const unsigned short* Bs0 = B + (n0b + (t >> 2)) * (long long)ldb + (t & 3) * 8;
  const unsigned short* Bs1 = Bs0 + 64LL * ldb;

  const int fr = lane & 15;
  const int ko = (lane >> 4) * 8;  // k element offset within 32

  f32x4 acc[4][4] = {};

  // LDS dests are wave-uniform (base + wid*1024B); HW adds lane*16B (rule #21:
  // linear dest; source pre-arranged so lane l covers row t>>2, col (t&3)*8).
  auto stage = [&](int k0, unsigned short* buf) {
    unsigned short* d = buf + wid * 512;
    gload_lds16(As0 + k0, d);            // A rows 0..63
    gload_lds16(As1 + k0, d + 2048);     // A rows 64..127
    gload_lds16(Bs0 + k0, d + 4096);     // B rows 0..63
    gload_lds16(Bs1 + k0, d + 6144);     // B rows 64..127
  };
  auto compute = [&](const unsigned short* buf) {
    const unsigned short* aF = buf + (wr * 64 + fr) * 32 + ko;
    const unsigned short* bF = buf + 4096 + (wc * 64 + fr) * 32 + ko;
    short8 a[4], b[4];
#pragma unroll
    for (int i = 0; i < 4; i++) {
      a[i] = *reinterpret_cast<const short8*>(aF + i * 512);  // +16 rows
      b[i] = *reinterpret_cast<const short8*>(bF + i * 512);
    }
#pragma unroll
    for (int mi = 0; mi < 4; mi++)
#pragma unroll
      for (int ni = 0; ni < 4; ni++)
        acc[mi][ni] =
            __builtin_amdgcn_mfma_f32_16x16x32_bf16(a[mi], b[ni], acc[mi][ni], 0, 0, 0);
  };

  stage(0, sAB[0]);
  __syncthreads();  // buf0 resident
  for (int k0 = 0; k0 < K; k0 += 64) {
    stage(k0 + 32, sAB[1]);            // in flight during compute (K%64==0 -> in bounds)
    compute(sAB[0]);
    __syncthreads();                   // drains vmcnt -> buf1 resident; buf0 reads done
    const int kn = (k0 + 64 < K) ? k0 + 64 : 0;  // last iter: harmless re-stage of 0
    stage(kn, sAB[0]);
    compute(sAB[1]);
    __syncthreads();
  }

  // epilogue: C/D mapping col=lane&15, row=(lane>>4)*4+r (verified)
  const int cr = (lane >> 4) * 4;
  const int cc = lane & 15;
#pragma unroll
  for (int mi = 0; mi < 4; mi++)
#pragma unroll
    for (int ni = 0; ni < 4; ni++)
#pragma unroll
      for (int r = 0; r < 4; r++) {
        long long row = m0b + wr * 64 + mi * 16 + cr + r;
        long long col = n0b + wc * 64 + ni * 16 + cc;
        float val = acc[mi][ni][r];
        if (OUT_BF16) {
          unsigned short* C = (unsigned short*)Cv + bz * sC;
          C[row * ldc + col] = f2bf(val);
        } else {
          float* C = (float*)Cv + bz * sC;
          C[row * ldc + col] = val;
        }
      }
}

// Row softmax over S=2048 fp32 scores; writes bf16 probs IN-PLACE at the row
// start (bf16 row stride = 2*S elements as seen by the PV GEMM).
__global__ __launch_bounds__(256) void softmax_rows(float* __restrict__ scores) {
  long long row = blockIdx.x;
  float* srow = scores + row * (long long)S_SZ;
  const int t = threadIdx.x;
  const int wid = t >> 6, lane = t & 63;

  float4v va = reinterpret_cast<const float4v*>(srow)[t];
  float4v vb = reinterpret_cast<const float4v*>(srow)[t + 256];
  float v[8] = {va.x * SCALE_F, va.y * SCALE_F, va.z * SCALE_F, va.w * SCALE_F,
                vb.x * SCALE_F, vb.y * SCALE_F, vb.z * SCALE_F, vb.w * SCALE_F};

  float m = v[0];
#pragma unroll
  for (int j = 1; j < 8; j++) m = fmaxf(m, v[j]);
#pragma unroll
  for (int off = 32; off; off >>= 1) m = fmaxf(m, __shfl_xor(m, off));

  __shared__ float redm[4];
  __shared__ float reds[4];
  if (lane == 0) redm[wid] = m;
  __syncthreads();  // also guarantees all loads of srow completed before stores
  m = fmaxf(fmaxf(redm[0], redm[1]), fmaxf(redm[2], redm[3]));

  float s = 0.f;
#pragma unroll
  for (int j = 0; j < 8; j++) {
    v[j] = __expf(v[j] - m);
    s += v[j];
  }
#pragma unroll
  for (int off = 32; off; off >>= 1) s += __shfl_xor(s, off);
  if (lane == 0) reds[wid] = s;
  __syncthreads();
  s = reds[0] + reds[1] + reds[2] + reds[3];
  float inv = 1.0f / s;

  u16x4 oa, ob;
  oa.x = f2bf(v[0] * inv); oa.y = f2bf(v[1] * inv);
  oa.z = f2bf(v[2] * inv); oa.w = f2bf(v[3] * inv);
  ob.x = f2bf(v[4] * inv); ob.y = f2bf(v[5] * inv);
  ob.z = f2bf(v[6] * inv); ob.w = f2bf(v[7] * inv);
  u16x4* prow4 = reinterpret_cast<u16x4*>(srow);
  prow4[t] = oa;
  prow4[t + 256] = ob;
}

extern "C" void kernel_launch(void* const* d_in, const int* in_sizes, int n_in,
                              void* d_out, int out_size, void* d_ws, size_t ws_size,
                              hipStream_t stream) {
  const float* tgt = (const float*)d_in[0];
  const float* mem = (const float*)d_in[1];
  const float* Wq  = (const float*)d_in[2];
  const float* Wk  = (const float*)d_in[3];
  const float* Wv  = (const float*)d_in[4];
  const float* Wo  = (const float*)d_in[5];
  float* out = (float*)d_out;

  // ---- workspace layout ----
  // NOTE: tgt_b/mem_b adjacent, wq_b/wk_b adjacent, q_b/k_b adjacent — the
  // merged q+k launch relies on this (grid.z = 8, z>=4 lands in mem/Wk/k).
  char* p = (char*)d_ws;
  unsigned short* tgt_b = (unsigned short*)p; p += (size_t)B_SZ * T_SZ * D_SZ * 2;  // reused as attn_out
  unsigned short* mem_b = (unsigned short*)p; p += (size_t)B_SZ * S_SZ * D_SZ * 2;
  unsigned short* wq_b  = (unsigned short*)p; p += (size_t)R_SZ * D_SZ * 2;
  unsigned short* wk_b  = (unsigned short*)p; p += (size_t)R_SZ * D_SZ * 2;
  unsigned short* wv_b  = (unsigned short*)p; p += (size_t)D_SZ * D_SZ * 2;
  unsigned short* wo_b  = (unsigned short*)p; p += (size_t)D_SZ * D_SZ * 2;
  unsigned short* q_b   = (unsigned short*)p; p += (size_t)B_SZ * T_SZ * R_SZ * 2;
  unsigned short* k_b   = (unsigned short*)p; p += (size_t)B_SZ * S_SZ * R_SZ * 2;
  unsigned short* vT_b  = (unsigned short*)p; p += (size_t)B_SZ * D_SZ * S_SZ * 2;
  float* scores = (float*)p;                  p += (size_t)B_SZ * T_SZ * S_SZ * 4;

  // ---- fp32 -> bf16 conversions (paired: z selects stream) ----
  {
    int n4 = (B_SZ * T_SZ * D_SZ) / 4;  // tgt & mem same size
    cvt_f32_bf16_x2<<<dim3(2048, 1, 2), dim3(256), 0, stream>>>(tgt, mem, tgt_b, mem_b, n4);
    int n4w = (R_SZ * D_SZ) / 4;        // Wq & Wk
    cvt_f32_bf16_x2<<<dim3(n4w / 256, 1, 2), dim3(256), 0, stream>>>(Wq, Wk, wq_b, wk_b, n4w);
    int n4v = (D_SZ * D_SZ) / 4;        // Wv & Wo
    cvt_f32_bf16_x2<<<dim3(n4v / 256, 1, 2), dim3(256), 0, stream>>>(Wv, Wo, wv_b, wo_b, n4v);
  }

  dim3 blk(256);

  // q & k merged: z<4 -> q = tgt@Wq^T ; z>=4 -> k = mem@Wk^T  (bzs=2).
  // Single n-tile (N=128): no panel refetch -> no swizzle.
  gemm_nt128<1, 0, 0><<<dim3(1, T_SZ / 128, 2 * B_SZ), blk, 0, stream>>>(
      tgt_b, wq_b, q_b, D_SZ, D_SZ, D_SZ, R_SZ, 2,
      (long long)T_SZ * D_SZ, (long long)R_SZ * D_SZ, (long long)T_SZ * R_SZ,
      0, 0, 0);

  // vT = Wv @ mem^T : [B,D,S]. Large operand = B (mem x-panels) -> x-slowest.
  gemm_nt128<1, 1, 1><<<dim3((S_SZ / 128) * (D_SZ / 128) * B_SZ), blk, 0, stream>>>(
      wv_b, mem_b, vT_b, D_SZ, D_SZ, D_SZ, S_SZ, 0,
      0LL, (long long)S_SZ * D_SZ, (long long)D_SZ * S_SZ,
      S_SZ / 128, D_SZ / 128, B_SZ);

  // scores = q @ k^T : [B,T,S] fp32. Per-batch q+k ~4MB -> batch-local (z-slowest).
  gemm_nt128<0, 2, 3><<<dim3((S_SZ / 128) * (T_SZ / 128) * B_SZ), blk, 0, stream>>>(
      q_b, k_b, scores, R_SZ, R_SZ, R_SZ, S_SZ, 0,
      (long long)T_SZ * R_SZ, (long long)S_SZ * R_SZ, (long long)T_SZ * S_SZ,
      S_SZ / 128, T_SZ / 128, B_SZ);

  // softmax rows, bf16 probs in-place (row stride 2*S bf16 elements)
  softmax_rows<<<dim3(B_SZ * T_SZ), blk, 0, stream>>>(scores);

  // attn_out = probs @ vT^T : [B,T,D] (reuse tgt_b). Large operand = B (vT x-panels).
  gemm_nt128<1, 3, 1><<<dim3((D_SZ / 128) * (T_SZ / 128) * B_SZ), blk, 0, stream>>>(
      (const unsigned short*)scores, vT_b, tgt_b, S_SZ, 2 * S_SZ, S_SZ, D_SZ, 0,
      2LL * T_SZ * S_SZ, (long long)D_SZ * S_SZ, (long long)T_SZ * D_SZ,
      D_SZ / 128, T_SZ / 128, B_SZ);

  // out = attn_out @ Wo^T : [B,T,D] fp32. Large operand = A (attn_out y-panels).
  gemm_nt128<0, 4, 2><<<dim3((D_SZ / 128) * (T_SZ / 128) * B_SZ), blk, 0, stream>>>(
      tgt_b, wo_b, out, D_SZ, D_SZ, D_SZ, D_SZ, 0,
      (long long)T_SZ * D_SZ, 0LL, (long long)T_SZ * D_SZ,
      D_SZ / 128, T_SZ / 128, B_SZ);
}

// Round 9
// 258.483 us; speedup vs baseline: 2.5951x; 1.0630x over previous
//
#include <hip/hip_runtime.h>
#include <hip/hip_bf16.h>

#define B_SZ 4
#define T_SZ 2048
#define S_SZ 2048
#define D_SZ 1024
#define R_SZ 128
#define SCALE_F 0.08838834764831845f  // 1/sqrt(128)

typedef __attribute__((ext_vector_type(8))) short short8;     // 8 x bf16 (raw bits)
typedef __attribute__((ext_vector_type(4))) float f32x4;
typedef __attribute__((ext_vector_type(4))) float float4v;
typedef __attribute__((ext_vector_type(4))) unsigned short u16x4;

// fp32 -> bf16 round-to-nearest-even, raw bits
__device__ __forceinline__ unsigned short f2bf(float f) {
  unsigned int u = __float_as_uint(f);
  unsigned int r = (u + 0x7FFFu + ((u >> 16) & 1u)) >> 16;
  return (unsigned short)r;
}

// async global->LDS, 16B per lane. LDS dest is wave-uniform base + lane*16.
__device__ __forceinline__ void gload_lds16(const unsigned short* g, unsigned short* l) {
  __builtin_amdgcn_global_load_lds(
      (const __attribute__((address_space(1))) unsigned int*)g,
      (__attribute__((address_space(3))) unsigned int*)l, 16, 0, 0);
}

// paired fp32->bf16 conversion: blockIdx.z selects (a->oa) or (b->ob)
__global__ __launch_bounds__(256) void cvt_f32_bf16_x2(
    const float* __restrict__ a, const float* __restrict__ b,
    unsigned short* __restrict__ oa, unsigned short* __restrict__ ob, int n4) {
  const float* src = blockIdx.z ? b : a;
  unsigned short* dst = blockIdx.z ? ob : oa;
  int i = blockIdx.x * blockDim.x + threadIdx.x;
  int stride = gridDim.x * blockDim.x;
  for (; i < n4; i += stride) {
    float4v v = reinterpret_cast<const float4v*>(src)[i];
    u16x4 o;
    o.x = f2bf(v.x); o.y = f2bf(v.y); o.z = f2bf(v.z); o.w = f2bf(v.w);
    reinterpret_cast<u16x4*>(dst)[i] = o;
  }
}

// C[M,N] = A[M,K] * B[N,K]^T  (NT form, bf16 in, fp32 acc).
// 128x128 block tile, BK=32, 4 waves (2x2) x 64x64 wave tile, 4x4 fragments of
// mfma_f32_16x16x32_bf16, global_load_lds width-16 staging, 2-phase
// double-buffered K-loop (one __syncthreads per K-step).
// EPI: 0 = fp32 store; 1 = bf16 store; 2 = exp(val*SCALE)->bf16 + row-sum
// atomics into lsum (max-free softmax numerator); 3 = bf16 store of val/l[row].
// SWZ (T1 XCD chunked swizzle; perf-only): 0 = plain 3D grid; else 1D grid,
// 1 = x-slowest, 2 = y-slowest, 3 = z-slowest.
template <int EPI, int SWZ>
__device__ __forceinline__ void gemm_core(
    const unsigned short* __restrict__ A,
    const unsigned short* __restrict__ B,
    void* __restrict__ Cv, float* __restrict__ lsum,
    int K, int lda, int ldb, int ldc, int bzs,
    long long sA, long long sB, long long sC,
    int GX, int GY, int GZ) {
  __shared__ unsigned short sAB[2][8192];  // per buf: A tile [128][32] @0, B tile @4096

  int bx, by, bz;
  if (SWZ == 0) {
    bx = blockIdx.x; by = blockIdx.y; bz = blockIdx.z;
  } else {
    const int cpx = (GX * GY * GZ) >> 3;
    const int lid = ((int)blockIdx.x & 7) * cpx + ((int)blockIdx.x >> 3);
    if (SWZ == 1) {
      bx = lid / (GY * GZ); int r = lid - bx * (GY * GZ); bz = r / GY; by = r - bz * GY;
    } else if (SWZ == 2) {
      by = lid / (GX * GZ); int r = lid - by * (GX * GZ); bz = r / GX; bx = r - bz * GX;
    } else {
      bz = lid / (GX * GY); int r = lid - bz * (GX * GY); by = r / GX; bx = r - by * GX;
    }
  }

  const int t = threadIdx.x;
  const int lane = t & 63;
  const int wid = t >> 6;
  const int wr = wid >> 1, wc = wid & 1;
  const long long m0b = (long long)by * 128;
  const long long n0b = (long long)bx * 128;

  A += (long long)bz * sA;
  B += (long long)(bz >> bzs) * sB;

  // staging source pointers (per-thread): row = base + t/4, col = (t&3)*8
  const unsigned short* As0 = A + (m0b + (t >> 2)) * (long long)lda + (t & 3) * 8;
  const unsigned short* As1 = As0 + 64LL * lda;
  const unsigned short* Bs0 = B + (n0b + (t >> 2)) * (long long)ldb + (t & 3) * 8;
  const unsigned short* Bs1 = Bs0 + 64LL * ldb;

  const int fr = lane & 15;
  const int ko = (lane >> 4) * 8;  // k element offset within 32

  f32x4 acc[4][4] = {};

  // LDS dests wave-uniform (base + wid*1024B); HW adds lane*16B (rule #21).
  auto stage = [&](int k0, unsigned short* buf) {
    unsigned short* d = buf + wid * 512;
    gload_lds16(As0 + k0, d);            // A rows 0..63
    gload_lds16(As1 + k0, d + 2048);     // A rows 64..127
    gload_lds16(Bs0 + k0, d + 4096);     // B rows 0..63
    gload_lds16(Bs1 + k0, d + 6144);     // B rows 64..127
  };
  auto compute = [&](const unsigned short* buf) {
    const unsigned short* aF = buf + (wr * 64 + fr) * 32 + ko;
    const unsigned short* bF = buf + 4096 + (wc * 64 + fr) * 32 + ko;
    short8 a[4], b[4];
#pragma unroll
    for (int i = 0; i < 4; i++) {
      a[i] = *reinterpret_cast<const short8*>(aF + i * 512);  // +16 rows
      b[i] = *reinterpret_cast<const short8*>(bF + i * 512);
    }
#pragma unroll
    for (int mi = 0; mi < 4; mi++)
#pragma unroll
      for (int ni = 0; ni < 4; ni++)
        acc[mi][ni] =
            __builtin_amdgcn_mfma_f32_16x16x32_bf16(a[mi], b[ni], acc[mi][ni], 0, 0, 0);
  };

  stage(0, sAB[0]);
  __syncthreads();  // buf0 resident
  for (int k0 = 0; k0 < K; k0 += 64) {
    stage(k0 + 32, sAB[1]);            // in flight during compute (K%64==0 -> in bounds)
    compute(sAB[0]);
    __syncthreads();                   // drains vmcnt; buf1 resident; buf0 reads done
    const int kn = (k0 + 64 < K) ? k0 + 64 : 0;  // last iter: harmless re-stage
    stage(kn, sAB[0]);
    compute(sAB[1]);
    __syncthreads();
  }

  // epilogue: C/D mapping col=lane&15, row=(lane>>4)*4+r (verified)
  const int cr = (lane >> 4) * 4;
  const int cc = lane & 15;

  if (EPI == 2) {
    // max-free softmax numerator: store exp, atomically accumulate row sums.
    unsigned short* C = (unsigned short*)Cv + bz * sC;
#pragma unroll
    for (int mi = 0; mi < 4; mi++) {
      float rs[4] = {0.f, 0.f, 0.f, 0.f};
#pragma unroll
      for (int ni = 0; ni < 4; ni++)
#pragma unroll
        for (int r = 0; r < 4; r++) {
          long long row = m0b + wr * 64 + mi * 16 + cr + r;
          long long col = n0b + wc * 64 + ni * 16 + cc;
          float e = __expf(acc[mi][ni][r] * SCALE_F);
          C[row * ldc + col] = f2bf(e);
          rs[r] += e;
        }
#pragma unroll
      for (int r = 0; r < 4; r++) {
        // reduce across the 16 lanes (cols) sharing this row
#pragma unroll
        for (int off = 1; off < 16; off <<= 1) rs[r] += __shfl_xor(rs[r], off);
        if (cc == 0)
          atomicAdd(&lsum[bz * T_SZ + m0b + wr * 64 + mi * 16 + cr + r], rs[r]);
      }
    }
  } else if (EPI == 3) {
    // normalize by row sum, store bf16
    unsigned short* C = (unsigned short*)Cv + bz * sC;
#pragma unroll
    for (int mi = 0; mi < 4; mi++)
#pragma unroll
      for (int r = 0; r < 4; r++) {
        long long row = m0b + wr * 64 + mi * 16 + cr + r;
        float invl = 1.0f / lsum[bz * T_SZ + row];
#pragma unroll
        for (int ni = 0; ni < 4; ni++) {
          long long col = n0b + wc * 64 + ni * 16 + cc;
          C[row * ldc + col] = f2bf(acc[mi][ni][r] * invl);
        }
      }
  } else {
#pragma unroll
    for (int mi = 0; mi < 4; mi++)
#pragma unroll
      for (int ni = 0; ni < 4; ni++)
#pragma unroll
        for (int r = 0; r < 4; r++) {
          long long row = m0b + wr * 64 + mi * 16 + cr + r;
          long long col = n0b + wc * 64 + ni * 16 + cc;
          float val = acc[mi][ni][r];
          if (EPI == 1) {
            unsigned short* C = (unsigned short*)Cv + bz * sC;
            C[row * ldc + col] = f2bf(val);
          } else {
            float* C = (float*)Cv + bz * sC;
            C[row * ldc + col] = val;
          }
        }
  }
}

#define GEMM_ARGS                                                              \
  const unsigned short *A, const unsigned short *B, void *Cv, float *lsum,     \
      int K, int lda, int ldb, int ldc, int bzs, long long sA, long long sB,   \
      long long sC, int GX, int GY, int GZ
#define GEMM_PASS A, B, Cv, lsum, K, lda, ldb, ldc, bzs, sA, sB, sC, GX, GY, GZ

// named wrappers -> per-GEMM rocprof attribution
__global__ __launch_bounds__(256) void gemm_qk(GEMM_ARGS)     { gemm_core<1, 0>(GEMM_PASS); }
__global__ __launch_bounds__(256) void gemm_vt(GEMM_ARGS)     { gemm_core<1, 1>(GEMM_PASS); }
__global__ __launch_bounds__(256) void gemm_scores(GEMM_ARGS) { gemm_core<2, 3>(GEMM_PASS); }
__global__ __launch_bounds__(256) void gemm_pv(GEMM_ARGS)     { gemm_core<3, 1>(GEMM_PASS); }
__global__ __launch_bounds__(256) void gemm_out(GEMM_ARGS)    { gemm_core<0, 2>(GEMM_PASS); }

extern "C" void kernel_launch(void* const* d_in, const int* in_sizes, int n_in,
                              void* d_out, int out_size, void* d_ws, size_t ws_size,
                              hipStream_t stream) {
  const float* tgt = (const float*)d_in[0];
  const float* mem = (const float*)d_in[1];
  const float* Wq  = (const float*)d_in[2];
  const float* Wk  = (const float*)d_in[3];
  const float* Wv  = (const float*)d_in[4];
  const float* Wo  = (const float*)d_in[5];
  float* out = (float*)d_out;

  // ---- workspace layout ----
  // tgt_b/mem_b adjacent, wq_b/wk_b adjacent, q_b/k_b adjacent (merged qk
  // launch: grid.z=8, z>=4 lands in mem/Wk/k via bzs=2 and sA/sB/sC strides).
  char* p = (char*)d_ws;
  unsigned short* tgt_b = (unsigned short*)p; p += (size_t)B_SZ * T_SZ * D_SZ * 2;  // reused as attn_out
  unsigned short* mem_b = (unsigned short*)p; p += (size_t)B_SZ * S_SZ * D_SZ * 2;
  unsigned short* wq_b  = (unsigned short*)p; p += (size_t)R_SZ * D_SZ * 2;
  unsigned short* wk_b  = (unsigned short*)p; p += (size_t)R_SZ * D_SZ * 2;
  unsigned short* wv_b  = (unsigned short*)p; p += (size_t)D_SZ * D_SZ * 2;
  unsigned short* wo_b  = (unsigned short*)p; p += (size_t)D_SZ * D_SZ * 2;
  unsigned short* q_b   = (unsigned short*)p; p += (size_t)B_SZ * T_SZ * R_SZ * 2;
  unsigned short* k_b   = (unsigned short*)p; p += (size_t)B_SZ * S_SZ * R_SZ * 2;
  unsigned short* vT_b  = (unsigned short*)p; p += (size_t)B_SZ * D_SZ * S_SZ * 2;
  unsigned short* probs = (unsigned short*)p; p += (size_t)B_SZ * T_SZ * S_SZ * 2;
  float* lsum = (float*)p;                    p += (size_t)B_SZ * T_SZ * 4;

  // ---- fp32 -> bf16 conversions (paired: z selects stream) ----
  {
    int n4 = (B_SZ * T_SZ * D_SZ) / 4;  // tgt & mem same size
    cvt_f32_bf16_x2<<<dim3(2048, 1, 2), dim3(256), 0, stream>>>(tgt, mem, tgt_b, mem_b, n4);
    int n4w = (R_SZ * D_SZ) / 4;        // Wq & Wk
    cvt_f32_bf16_x2<<<dim3(n4w / 256, 1, 2), dim3(256), 0, stream>>>(Wq, Wk, wq_b, wk_b, n4w);
    int n4v = (D_SZ * D_SZ) / 4;        // Wv & Wo
    cvt_f32_bf16_x2<<<dim3(n4v / 256, 1, 2), dim3(256), 0, stream>>>(Wv, Wo, wv_b, wo_b, n4v);
  }

  dim3 blk(256);

  // q & k merged: z<4 -> q = tgt@Wq^T ; z>=4 -> k = mem@Wk^T  (bzs=2).
  gemm_qk<<<dim3(1, T_SZ / 128, 2 * B_SZ), blk, 0, stream>>>(
      tgt_b, wq_b, q_b, nullptr, D_SZ, D_SZ, D_SZ, R_SZ, 2,
      (long long)T_SZ * D_SZ, (long long)R_SZ * D_SZ, (long long)T_SZ * R_SZ,
      0, 0, 0);

  // vT = Wv @ mem^T : [B,D,S]
  gemm_vt<<<dim3((S_SZ / 128) * (D_SZ / 128) * B_SZ), blk, 0, stream>>>(
      wv_b, mem_b, vT_b, nullptr, D_SZ, D_SZ, D_SZ, S_SZ, 0,
      0LL, (long long)S_SZ * D_SZ, (long long)D_SZ * S_SZ,
      S_SZ / 128, D_SZ / 128, B_SZ);

  // zero row-sum accumulator (re-poisoned to 0xAA before every timed call)
  hipMemsetAsync(lsum, 0, (size_t)B_SZ * T_SZ * 4, stream);

  // probs = exp(q@k^T * SCALE) bf16 [B,T,S] + lsum row sums (max-free softmax)
  gemm_scores<<<dim3((S_SZ / 128) * (T_SZ / 128) * B_SZ), blk, 0, stream>>>(
      q_b, k_b, probs, lsum, R_SZ, R_SZ, R_SZ, S_SZ, 0,
      (long long)T_SZ * R_SZ, (long long)S_SZ * R_SZ, (long long)T_SZ * S_SZ,
      S_SZ / 128, T_SZ / 128, B_SZ);

  // attn_out = (probs @ vT^T) / lsum : [B,T,D] bf16 (reuse tgt_b)
  gemm_pv<<<dim3((D_SZ / 128) * (T_SZ / 128) * B_SZ), blk, 0, stream>>>(
      probs, vT_b, tgt_b, lsum, S_SZ, S_SZ, S_SZ, D_SZ, 0,
      (long long)T_SZ * S_SZ, (long long)D_SZ * S_SZ, (long long)T_SZ * D_SZ,
      D_SZ / 128, T_SZ / 128, B_SZ);

  // out = attn_out @ Wo^T : [B,T,D] fp32 -> d_out
  gemm_out<<<dim3((D_SZ / 128) * (T_SZ / 128) * B_SZ), blk, 0, stream>>>(
      tgt_b, wo_b, out, nullptr, D_SZ, D_SZ, D_SZ, D_SZ, 0,
      (long long)T_SZ * D_SZ, 0LL, (long long)T_SZ * D_SZ,
      D_SZ / 128, T_SZ / 128, B_SZ);
}

// Round 12
// 247.319 us; speedup vs baseline: 2.7123x; 1.0451x over previous
//
#include <hip/hip_runtime.h>
#include <hip/hip_bf16.h>

#define B_SZ 4
#define T_SZ 2048
#define S_SZ 2048
#define D_SZ 1024
#define R_SZ 128
#define SCALE_F 0.08838834764831845f  // 1/sqrt(128)

typedef __attribute__((ext_vector_type(8))) short short8;     // 8 x bf16 (raw bits)
typedef __attribute__((ext_vector_type(4))) float f32x4;
typedef __attribute__((ext_vector_type(4))) float float4v;
typedef __attribute__((ext_vector_type(4))) unsigned short u16x4;

// fp32 -> bf16 round-to-nearest-even, raw bits
__device__ __forceinline__ unsigned short f2bf(float f) {
  unsigned int u = __float_as_uint(f);
  unsigned int r = (u + 0x7FFFu + ((u >> 16) & 1u)) >> 16;
  return (unsigned short)r;
}

// async global->LDS, 16B per lane. LDS dest is wave-uniform base + lane*16.
__device__ __forceinline__ void gload_lds16(const unsigned short* g, unsigned short* l) {
  __builtin_amdgcn_global_load_lds(
      (const __attribute__((address_space(1))) unsigned int*)g,
      (__attribute__((address_space(3))) unsigned int*)l, 16, 0, 0);
}

__global__ __launch_bounds__(256) void cvt_f32_bf16(const float* __restrict__ in,
                                                    unsigned short* __restrict__ out,
                                                    int n4) {
  int i = blockIdx.x * blockDim.x + threadIdx.x;
  int stride = gridDim.x * blockDim.x;
  for (; i < n4; i += stride) {
    float4v v = reinterpret_cast<const float4v*>(in)[i];
    u16x4 o;
    o.x = f2bf(v.x); o.y = f2bf(v.y); o.z = f2bf(v.z); o.w = f2bf(v.w);
    reinterpret_cast<u16x4*>(out)[i] = o;
  }
}

// paired fp32->bf16 conversion: blockIdx.z selects (a->oa) or (b->ob)
__global__ __launch_bounds__(256) void cvt_f32_bf16_x2(
    const float* __restrict__ a, const float* __restrict__ b,
    unsigned short* __restrict__ oa, unsigned short* __restrict__ ob, int n4) {
  const float* src = blockIdx.z ? b : a;
  unsigned short* dst = blockIdx.z ? ob : oa;
  int i = blockIdx.x * blockDim.x + threadIdx.x;
  int stride = gridDim.x * blockDim.x;
  for (; i < n4; i += stride) {
    float4v v = reinterpret_cast<const float4v*>(src)[i];
    u16x4 o;
    o.x = f2bf(v.x); o.y = f2bf(v.y); o.z = f2bf(v.z); o.w = f2bf(v.w);
    reinterpret_cast<u16x4*>(dst)[i] = o;
  }
}

// transpose + cvt: in fp32 [n][n] row-major -> out bf16 [n][n] = in^T.
// 64x64 LDS tiles, float tile[64][65] (padded), grid (n/64, n/64).
__global__ __launch_bounds__(256) void cvt_transpose_bf16(
    const float* __restrict__ in, unsigned short* __restrict__ outp, int n) {
  __shared__ float tile[64][65];
  const int t = threadIdx.x;
  const int c4 = (t & 15) * 4;     // col within tile (x4)
  const int r0 = t >> 4;           // row 0..15 (stride 16)
  const int x0 = blockIdx.x * 64;  // input col base
  const int y0 = blockIdx.y * 64;  // input row base
#pragma unroll
  for (int rr = 0; rr < 64; rr += 16) {
    float4v v = *reinterpret_cast<const float4v*>(&in[(long long)(y0 + r0 + rr) * n + x0 + c4]);
    tile[r0 + rr][c4] = v.x; tile[r0 + rr][c4 + 1] = v.y;
    tile[r0 + rr][c4 + 2] = v.z; tile[r0 + rr][c4 + 3] = v.w;
  }
  __syncthreads();
#pragma unroll
  for (int rr = 0; rr < 64; rr += 16) {
    u16x4 o;
    o.x = f2bf(tile[c4][r0 + rr]);     o.y = f2bf(tile[c4 + 1][r0 + rr]);
    o.z = f2bf(tile[c4 + 2][r0 + rr]); o.w = f2bf(tile[c4 + 3][r0 + rr]);
    *reinterpret_cast<u16x4*>(&outp[(long long)(x0 + r0 + rr) * n + y0 + c4]) = o;
  }
}

// C[M,N] = A[M,K] * B[N,K]^T  (NT form, bf16 in, fp32 acc).
// 128x128 block tile, BK=32, 4 waves (2x2) x 64x64 wave tile, 4x4 fragments of
// mfma_f32_16x16x32_bf16, global_load_lds width-16 staging, 2-phase
// double-buffered K-loop (one __syncthreads per K-step).
// EPI: 0 = fp32 store; 1 = bf16 store; 2 = exp(val*SCALE)->bf16 + row-sum
// atomics into lsum; 3 = fp32 store of val/lsum[row] (fused PV+normalize).
// SWZ (T1 XCD chunked swizzle; perf-only): 0 = plain 3D grid; else 1D grid,
// 1 = x-slowest, 2 = y-slowest, 3 = z-slowest.
template <int EPI, int SWZ>
__device__ __forceinline__ void gemm_core(
    const unsigned short* __restrict__ A,
    const unsigned short* __restrict__ B,
    void* __restrict__ Cv, float* __restrict__ lsum,
    int K, int lda, int ldb, int ldc, int bzs,
    long long sA, long long sB, long long sC,
    int GX, int GY, int GZ) {
  __shared__ unsigned short sAB[2][8192];  // per buf: A tile [128][32] @0, B tile @4096

  int bx, by, bz;
  if (SWZ == 0) {
    bx = blockIdx.x; by = blockIdx.y; bz = blockIdx.z;
  } else {
    const int cpx = (GX * GY * GZ) >> 3;
    const int lid = ((int)blockIdx.x & 7) * cpx + ((int)blockIdx.x >> 3);
    if (SWZ == 1) {
      bx = lid / (GY * GZ); int r = lid - bx * (GY * GZ); bz = r / GY; by = r - bz * GY;
    } else if (SWZ == 2) {
      by = lid / (GX * GZ); int r = lid - by * (GX * GZ); bz = r / GX; bx = r - bz * GX;
    } else {
      bz = lid / (GX * GY); int r = lid - bz * (GX * GY); by = r / GX; bx = r - by * GX;
    }
  }

  const int t = threadIdx.x;
  const int lane = t & 63;
  const int wid = t >> 6;
  const int wr = wid >> 1, wc = wid & 1;
  const long long m0b = (long long)by * 128;
  const long long n0b = (long long)bx * 128;

  A += (long long)bz * sA;
  B += (long long)(bz >> bzs) * sB;

  // staging source pointers (per-thread): row = base + t/4, col = (t&3)*8
  const unsigned short* As0 = A + (m0b + (t >> 2)) * (long long)lda + (t & 3) * 8;
  const unsigned short* As1 = As0 + 64LL * lda;
  const unsigned short* Bs0 = B + (n0b + (t >> 2)) * (long long)ldb + (t & 3) * 8;
  const unsigned short* Bs1 = Bs0 + 64LL * ldb;

  const int fr = lane & 15;
  const int ko = (lane >> 4) * 8;  // k element offset within 32

  f32x4 acc[4][4] = {};

  // LDS dests wave-uniform (base + wid*1024B); HW adds lane*16B (rule #21).
  auto stage = [&](int k0, unsigned short* buf) {
    unsigned short* d = buf + wid * 512;
    gload_lds16(As0 + k0, d);            // A rows 0..63
    gload_lds16(As1 + k0, d + 2048);     // A rows 64..127
    gload_lds16(Bs0 + k0, d + 4096);     // B rows 0..63
    gload_lds16(Bs1 + k0, d + 6144);     // B rows 64..127
  };
  auto compute = [&](const unsigned short* buf) {
    const unsigned short* aF = buf + (wr * 64 + fr) * 32 + ko;
    const unsigned short* bF = buf + 4096 + (wc * 64 + fr) * 32 + ko;
    short8 a[4], b[4];
#pragma unroll
    for (int i = 0; i < 4; i++) {
      a[i] = *reinterpret_cast<const short8*>(aF + i * 512);  // +16 rows
      b[i] = *reinterpret_cast<const short8*>(bF + i * 512);
    }
#pragma unroll
    for (int mi = 0; mi < 4; mi++)
#pragma unroll
      for (int ni = 0; ni < 4; ni++)
        acc[mi][ni] =
            __builtin_amdgcn_mfma_f32_16x16x32_bf16(a[mi], b[ni], acc[mi][ni], 0, 0, 0);
  };

  stage(0, sAB[0]);
  __syncthreads();  // buf0 resident
  for (int k0 = 0; k0 < K; k0 += 64) {
    stage(k0 + 32, sAB[1]);            // in flight during compute (K%64==0 -> in bounds)
    compute(sAB[0]);
    __syncthreads();                   // drains vmcnt; buf1 resident; buf0 reads done
    const int kn = (k0 + 64 < K) ? k0 + 64 : 0;  // last iter: harmless re-stage
    stage(kn, sAB[0]);
    compute(sAB[1]);
    __syncthreads();
  }

  // epilogue: C/D mapping col=lane&15, row=(lane>>4)*4+r (verified)
  const int cr = (lane >> 4) * 4;
  const int cc = lane & 15;

  if (EPI == 2) {
    // max-free softmax numerator: store exp, atomically accumulate row sums.
    unsigned short* C = (unsigned short*)Cv + bz * sC;
#pragma unroll
    for (int mi = 0; mi < 4; mi++) {
      float rs[4] = {0.f, 0.f, 0.f, 0.f};
#pragma unroll
      for (int ni = 0; ni < 4; ni++)
#pragma unroll
        for (int r = 0; r < 4; r++) {
          long long row = m0b + wr * 64 + mi * 16 + cr + r;
          long long col = n0b + wc * 64 + ni * 16 + cc;
          float e = __expf(acc[mi][ni][r] * SCALE_F);
          C[row * ldc + col] = f2bf(e);
          rs[r] += e;
        }
#pragma unroll
      for (int r = 0; r < 4; r++) {
        // reduce across the 16 lanes (cols) sharing this row
#pragma unroll
        for (int off = 1; off < 16; off <<= 1) rs[r] += __shfl_xor(rs[r], off);
        if (cc == 0)
          atomicAdd(&lsum[bz * T_SZ + m0b + wr * 64 + mi * 16 + cr + r], rs[r]);
      }
    }
  } else if (EPI == 3) {
    // fused PV+out-proj epilogue: normalize by row sum, store fp32
    float* C = (float*)Cv + bz * sC;
#pragma unroll
    for (int mi = 0; mi < 4; mi++)
#pragma unroll
      for (int r = 0; r < 4; r++) {
        long long row = m0b + wr * 64 + mi * 16 + cr + r;
        float invl = 1.0f / lsum[bz * T_SZ + row];
#pragma unroll
        for (int ni = 0; ni < 4; ni++) {
          long long col = n0b + wc * 64 + ni * 16 + cc;
          C[row * ldc + col] = acc[mi][ni][r] * invl;
        }
      }
  } else {
#pragma unroll
    for (int mi = 0; mi < 4; mi++)
#pragma unroll
      for (int ni = 0; ni < 4; ni++)
#pragma unroll
        for (int r = 0; r < 4; r++) {
          long long row = m0b + wr * 64 + mi * 16 + cr + r;
          long long col = n0b + wc * 64 + ni * 16 + cc;
          float val = acc[mi][ni][r];
          if (EPI == 1) {
            unsigned short* C = (unsigned short*)Cv + bz * sC;
            C[row * ldc + col] = f2bf(val);
          } else {
            float* C = (float*)Cv + bz * sC;
            C[row * ldc + col] = val;
          }
        }
  }
}

#define GEMM_ARGS                                                              \
  const unsigned short *A, const unsigned short *B, void *Cv, float *lsum,     \
      int K, int lda, int ldb, int ldc, int bzs, long long sA, long long sB,   \
      long long sC, int GX, int GY, int GZ
#define GEMM_PASS A, B, Cv, lsum, K, lda, ldb, ldc, bzs, sA, sB, sC, GX, GY, GZ

// named wrappers -> per-GEMM rocprof attribution
__global__ __launch_bounds__(256) void gemm_wvo(GEMM_ARGS)    { gemm_core<1, 0>(GEMM_PASS); }
__global__ __launch_bounds__(256) void gemm_qk(GEMM_ARGS)     { gemm_core<1, 0>(GEMM_PASS); }
__global__ __launch_bounds__(256) void gemm_v2t(GEMM_ARGS)    { gemm_core<1, 1>(GEMM_PASS); }
__global__ __launch_bounds__(256) void gemm_scores(GEMM_ARGS) { gemm_core<2, 3>(GEMM_PASS); }
__global__ __launch_bounds__(256) void gemm_pvout(GEMM_ARGS)  { gemm_core<3, 1>(GEMM_PASS); }

extern "C" void kernel_launch(void* const* d_in, const int* in_sizes, int n_in,
                              void* d_out, int out_size, void* d_ws, size_t ws_size,
                              hipStream_t stream) {
  const float* tgt = (const float*)d_in[0];
  const float* mem = (const float*)d_in[1];
  const float* Wq  = (const float*)d_in[2];
  const float* Wk  = (const float*)d_in[3];
  const float* Wv  = (const float*)d_in[4];
  const float* Wo  = (const float*)d_in[5];
  float* out = (float*)d_out;

  // ---- workspace layout ----
  // tgt_b/mem_b adjacent, wq_b/wk_b adjacent, q_b/k_b adjacent (merged qk
  // launch: grid.z=8, z>=4 lands in mem/Wk/k via bzs=2 and sA/sB/sC strides).
  char* p = (char*)d_ws;
  unsigned short* tgt_b = (unsigned short*)p; p += (size_t)B_SZ * T_SZ * D_SZ * 2;
  unsigned short* mem_b = (unsigned short*)p; p += (size_t)B_SZ * S_SZ * D_SZ * 2;
  unsigned short* wq_b  = (unsigned short*)p; p += (size_t)R_SZ * D_SZ * 2;
  unsigned short* wk_b  = (unsigned short*)p; p += (size_t)R_SZ * D_SZ * 2;
  unsigned short* wo_b  = (unsigned short*)p; p += (size_t)D_SZ * D_SZ * 2;
  unsigned short* wvT_b = (unsigned short*)p; p += (size_t)D_SZ * D_SZ * 2;  // Wv^T bf16
  unsigned short* wvo_b = (unsigned short*)p; p += (size_t)D_SZ * D_SZ * 2;  // Wo@Wv bf16
  unsigned short* q_b   = (unsigned short*)p; p += (size_t)B_SZ * T_SZ * R_SZ * 2;
  unsigned short* k_b   = (unsigned short*)p; p += (size_t)B_SZ * S_SZ * R_SZ * 2;
  unsigned short* v2T_b = (unsigned short*)p; p += (size_t)B_SZ * D_SZ * S_SZ * 2;  // (mem@Wvo^T)^T
  unsigned short* probs = (unsigned short*)p; p += (size_t)B_SZ * T_SZ * S_SZ * 2;
  float* lsum = (float*)p;                    p += (size_t)B_SZ * T_SZ * 4;

  // ---- conversions ----
  {
    int n4 = (B_SZ * T_SZ * D_SZ) / 4;  // tgt & mem same size
    cvt_f32_bf16_x2<<<dim3(2048, 1, 2), dim3(256), 0, stream>>>(tgt, mem, tgt_b, mem_b, n4);
    int n4w = (R_SZ * D_SZ) / 4;        // Wq & Wk
    cvt_f32_bf16_x2<<<dim3(n4w / 256, 1, 2), dim3(256), 0, stream>>>(Wq, Wk, wq_b, wk_b, n4w);
    int n4v = (D_SZ * D_SZ) / 4;        // Wo
    cvt_f32_bf16<<<dim3(n4v / 256), dim3(256), 0, stream>>>(Wo, wo_b, n4v);
    // Wv fp32 [e][d] -> wvT bf16 [d][e]
    cvt_transpose_bf16<<<dim3(D_SZ / 64, D_SZ / 64), dim3(256), 0, stream>>>(Wv, wvT_b, D_SZ);
  }

  dim3 blk(256);

  // Wvo = Wo @ Wv : [o][d]  (NT: A=Wo[o][e], B=wvT[d][e])
  gemm_wvo<<<dim3(D_SZ / 128, D_SZ / 128, 1), blk, 0, stream>>>(
      wo_b, wvT_b, wvo_b, nullptr, D_SZ, D_SZ, D_SZ, D_SZ, 0,
      0LL, 0LL, 0LL, 0, 0, 0);

  // q & k merged: z<4 -> q = tgt@Wq^T ; z>=4 -> k = mem@Wk^T  (bzs=2).
  gemm_qk<<<dim3(1, T_SZ / 128, 2 * B_SZ), blk, 0, stream>>>(
      tgt_b, wq_b, q_b, nullptr, D_SZ, D_SZ, D_SZ, R_SZ, 2,
      (long long)T_SZ * D_SZ, (long long)R_SZ * D_SZ, (long long)T_SZ * R_SZ,
      0, 0, 0);

  // v2T = Wvo @ mem^T : [B,D,S]  (folds Wo into V; PV output is then final)
  gemm_v2t<<<dim3((S_SZ / 128) * (D_SZ / 128) * B_SZ), blk, 0, stream>>>(
      wvo_b, mem_b, v2T_b, nullptr, D_SZ, D_SZ, D_SZ, S_SZ, 0,
      0LL, (long long)S_SZ * D_SZ, (long long)D_SZ * S_SZ,
      S_SZ / 128, D_SZ / 128, B_SZ);

  // zero row-sum accumulator
  hipMemsetAsync(lsum, 0, (size_t)B_SZ * T_SZ * 4, stream);

  // probs = exp(q@k^T * SCALE) bf16 [B,T,S] + lsum row sums (max-free softmax)
  gemm_scores<<<dim3((S_SZ / 128) * (T_SZ / 128) * B_SZ), blk, 0, stream>>>(
      q_b, k_b, probs, lsum, R_SZ, R_SZ, R_SZ, S_SZ, 0,
      (long long)T_SZ * R_SZ, (long long)S_SZ * R_SZ, (long long)T_SZ * S_SZ,
      S_SZ / 128, T_SZ / 128, B_SZ);

  // out = (probs @ v2T^T) / lsum : [B,T,D] fp32 -> d_out directly
  gemm_pvout<<<dim3((D_SZ / 128) * (T_SZ / 128) * B_SZ), blk, 0, stream>>>(
      probs, v2T_b, out, lsum, S_SZ, S_SZ, S_SZ, D_SZ, 0,
      (long long)T_SZ * S_SZ, (long long)D_SZ * S_SZ, (long long)T_SZ * D_SZ,
      D_SZ / 128, T_SZ / 128, B_SZ);
}